// Round 7
// baseline (2140.402 us; speedup 1.0000x reference)
//
#include <hip/hip_runtime.h>

constexpr int kB   = 4;
constexpr int kNEG = 33;
constexpr int kN   = 10000;
constexpr int kR   = 256;
constexpr int kD   = 64;
constexpr int kL   = 6;
constexpr int kE   = 200000;
constexpr int kER  = 80000;

typedef const float* fp;

__device__ __forceinline__ float rdlane(float v, int l) {
  return __uint_as_float(__builtin_amdgcn_readlane(__float_as_uint(v), l));
}
__device__ __forceinline__ float wave_sum64(float v) {
  #pragma unroll
  for (int o = 32; o > 0; o >>= 1) v += __shfl_xor(v, o, 64);
  return v;
}

// ---------------- utility ----------------
__global__ void k_fill(float* __restrict__ p, float v, int n) {
  int i = blockIdx.x * blockDim.x + threadIdx.x;
  int stride = gridDim.x * blockDim.x;
  for (; i < n; i += stride) p[i] = v;
}
__global__ void k_zero_i(int* __restrict__ p, int n) {
  int i = blockIdx.x * blockDim.x + threadIdx.x;
  int stride = gridDim.x * blockDim.x;
  for (; i < n; i += stride) p[i] = 0;
}
__global__ void k_add_row(float* __restrict__ dst, const int* __restrict__ batch) {
  int tid = threadIdx.x;
  int b = tid >> 6, d = tid & 63;
  int row = batch[b * kNEG * 3 + 2];
  dst[((size_t)b * kR + row) * 64 + d] += 1.0f;
}
__global__ void k_get_q(float* __restrict__ q, const float* __restrict__ relx,
                        const int* __restrict__ batch) {
  int tid = threadIdx.x;
  int b = tid >> 6, d = tid & 63;
  int r0 = batch[b * kNEG * 3 + 2];
  q[b * 64 + d] = relx[((size_t)b * kR + r0) * 64 + d];
}
// transpose 64x64 matrices: out[m][j][k] = in[m][k][j]
__global__ void k_transpose64(const float* __restrict__ in, float* __restrict__ out) {
  int m = blockIdx.x;
  const float* A = in + (size_t)m * 4096;
  float* B = out + (size_t)m * 4096;
  for (int i = threadIdx.x; i < 4096; i += 256) {
    int k = i >> 6, j = i & 63;
    B[j * 64 + k] = A[k * 64 + j];
  }
}

// ---------------- CSR build ----------------
__global__ void k_hist(const int* __restrict__ dst, int ne, int* __restrict__ cnt) {
  int i = blockIdx.x * blockDim.x + threadIdx.x;
  if (i < ne) atomicAdd(&cnt[dst[i]], 1);
}
__global__ void k_hist_rel(const int* __restrict__ rel_dst, int* __restrict__ cnt) {
  int g = blockIdx.y;
  int i = blockIdx.x * blockDim.x + threadIdx.x;
  if (i < kER) atomicAdd(&cnt[g * 256 + rel_dst[(size_t)g * kER + i]], 1);
}
__global__ void k_scan_multi(const int* __restrict__ cnt, int* __restrict__ start,
                             int* __restrict__ cursor, int n, int cstride, int sstride) {
  const int* c = cnt + (size_t)blockIdx.x * cstride;
  int* st = start + (size_t)blockIdx.x * sstride;
  int* cu = cursor + (size_t)blockIdx.x * sstride;
  __shared__ int part[256];
  int t = threadIdx.x;
  int chunk = (n + 255) / 256;
  int lo = t * chunk, hi = min(lo + chunk, n);
  int s = 0;
  for (int i = lo; i < hi; ++i) s += c[i];
  part[t] = s;
  __syncthreads();
  if (t == 0) { int run = 0; for (int i = 0; i < 256; ++i) { int v = part[i]; part[i] = run; run += v; } }
  __syncthreads();
  int run = part[t];
  for (int i = lo; i < hi; ++i) { st[i] = run; cu[i] = run; run += c[i]; }
  if (t == 255) st[n] = run;
}
__global__ void k_fill_csr(const int* __restrict__ src, const int* __restrict__ dst,
                           const int* __restrict__ et, int ne,
                           int* __restrict__ cursor, int2* __restrict__ out) {
  int i = blockIdx.x * blockDim.x + threadIdx.x;
  if (i < ne) {
    int p = atomicAdd(&cursor[dst[i]], 1);
    out[p] = make_int2(src[i], et[i]);
  }
}
__global__ void k_fill_csr_rel(const int* __restrict__ src, const int* __restrict__ dst,
                               const int* __restrict__ et,
                               int* __restrict__ cursor, int2* __restrict__ out) {
  int g = blockIdx.y;
  int i = blockIdx.x * blockDim.x + threadIdx.x;
  if (i < kER) {
    int p = atomicAdd(&cursor[g * 257 + dst[(size_t)g * kER + i]], 1);
    out[(size_t)g * kER + p] = make_int2(src[(size_t)g * kER + i], et[(size_t)g * kER + i]);
  }
}

// ---------------- rel-gate MLP for entity phase: all 6 layers, row per wave ----------------
__global__ void __launch_bounds__(256) k_mlp_rel6(
    const float* __restrict__ in, fp p1w, fp p1b, fp p2w, fp p2b,
    float* __restrict__ out) {
  int j = blockIdx.y;                               // layer
  int row = blockIdx.x * 4 + (threadIdx.x >> 6);    // 256 blocks * 4 waves = 1024 rows
  int lane = threadIdx.x & 63;
  fp W1 = p1w + (size_t)j * 4096;
  fp W2 = p2w + (size_t)j * 4096;
  float xv = in[(size_t)row * 64 + lane];
  float a = p1b[j * 64 + lane];
  float wbuf[8];
  #pragma unroll
  for (int kk = 0; kk < 64; kk += 8) {
    #pragma unroll
    for (int u = 0; u < 8; ++u) wbuf[u] = W1[(kk + u) * 64 + lane];
    #pragma unroll
    for (int u = 0; u < 8; ++u) a = fmaf(rdlane(xv, kk + u), wbuf[u], a);
  }
  a = fmaxf(a, 0.f);
  float c = p2b[j * 64 + lane];
  #pragma unroll
  for (int kk = 0; kk < 64; kk += 8) {
    #pragma unroll
    for (int u = 0; u < 8; ++u) wbuf[u] = W2[(kk + u) * 64 + lane];
    #pragma unroll
    for (int u = 0; u < 8; ++u) c = fmaf(rdlane(a, kk + u), wbuf[u], c);
  }
  out[((size_t)j * kB * kR + row) * 64 + lane] = c;
}

// ---------------- lane=row gate MLP over node_reps (transposed weights) ----------------
// one wave (64 threads) per 64 rows; lane owns a full row in registers.
// W^T rows are wave-uniform -> scalar-pipe loads; every VALU op is an FMA.
__global__ void __launch_bounds__(64) k_mlp_rowsT(
    const float* __restrict__ in,        // [40000][64]
    const float* __restrict__ w1t,       // [24][64][64] (j-major)
    const float* __restrict__ b1,        // [24][64]
    const float* __restrict__ w2t,
    const float* __restrict__ b2,
    int layer, float* __restrict__ out)  // [4][40000][64]
{
  int g = blockIdx.y;
  int pg = g * kL + layer;
  int lane = threadIdx.x;
  int row = blockIdx.x * 64 + lane;      // 625 blocks -> rows 0..39999
  __shared__ float h[64][65];
  const float* xrow = in + (size_t)row * 64;
  float x[64];
  #pragma unroll
  for (int k = 0; k < 64; ++k) x[k] = xrow[k];
  const float* W1 = w1t + (size_t)pg * 4096;
  const float* B1 = b1 + pg * 64;
  #pragma unroll 1
  for (int j = 0; j < 64; ++j) {
    const float* wr = W1 + j * 64;
    float acc = B1[j];
    #pragma unroll
    for (int k = 0; k < 64; ++k) acc = fmaf(x[k], wr[k], acc);
    h[lane][j] = fmaxf(acc, 0.f);
  }
  __syncthreads();
  float hh[64];
  #pragma unroll
  for (int k = 0; k < 64; ++k) hh[k] = h[lane][k];
  const float* W2 = w2t + (size_t)pg * 4096;
  const float* B2 = b2 + pg * 64;
  #pragma unroll 1
  for (int j = 0; j < 64; ++j) {
    const float* wr = W2 + j * 64;
    float acc = B2[j];
    #pragma unroll
    for (int k = 0; k < 64; ++k) acc = fmaf(hh[k], wr[k], acc);
    h[lane][j] = acc;                    // reuse LDS as out staging
  }
  __syncthreads();
  float* orow = out + (size_t)g * kB * kN * 64 + (size_t)blockIdx.x * 64 * 64;
  #pragma unroll
  for (int rr = 0; rr < 64; ++rr)
    orow[rr * 64 + lane] = h[rr][lane];  // coalesced writeout
}

// ---------------- i=0 rel specials ----------------
__global__ void k_gate0(fp p1w, fp p1b, fp p2w, fp p2b, float* __restrict__ gate0) {
  int g = threadIdx.x >> 6, lane = threadIdx.x & 63;
  int pg = g * kL;
  float a = p1b[pg * 64 + lane];
  #pragma unroll
  for (int k = 0; k < 64; ++k) a += p1w[(size_t)pg * 4096 + k * 64 + lane];
  a = fmaxf(a, 0.f);
  float c = p2b[pg * 64 + lane];
  #pragma unroll
  for (int k = 0; k < 64; ++k)
    c = fmaf(rdlane(a, k), p2w[(size_t)pg * 4096 + k * 64 + lane], c);
  gate0[g * 64 + lane] = c;
}
__global__ void k_rel_agg0(const int* __restrict__ rel_start, const int2* __restrict__ rel_edges,
                           const int* __restrict__ batch, const float* __restrict__ gate0,
                           float* __restrict__ agg) {
  int wid = (blockIdx.x * blockDim.x + threadIdx.x) >> 6;  // g*1024 + b*256 + r
  int lane = threadIdx.x & 63;
  int g = wid >> 10, rem = wid & 1023, b = rem >> 8, r = rem & 255;
  int r0 = batch[b * kNEG * 3 + 2];
  const int* start = rel_start + g * 257;
  const int2* edges = rel_edges + (size_t)g * kER;
  int s0 = start[r], s1 = start[r + 1];
  int cnt = 0;
  for (int base = s0; base < s1; base += 64) {
    int e = base + lane;
    bool m = false;
    if (e < s1) m = (edges[e].x == r0);
    cnt += (int)__popcll(__ballot(m));
  }
  agg[(size_t)wid * 64 + lane] = gate0[g * 64 + lane] * (float)cnt + ((r == r0) ? 1.f : 0.f);
}

// ---------------- rel gather (dense gates), blockIdx.y = g ----------------
__global__ void __launch_bounds__(256) k_gather_rel_all(
    const float* __restrict__ x, const float* __restrict__ gateN,
    const int* __restrict__ rel_start, const int2* __restrict__ rel_edges,
    const int* __restrict__ batch, float* __restrict__ agg) {
  int g = blockIdx.y;
  const float* gate = gateN + (size_t)g * kB * kN * 64;
  const int* start = rel_start + g * 257;
  const int2* edges = rel_edges + (size_t)g * kER;
  int blk = blockIdx.x;              // b*kR + r
  int b = blk >> 8, r = blk & 255;
  int w = threadIdx.x >> 6, lane = threadIdx.x & 63;
  const float* xb = x + (size_t)b * kR * 64 + lane;
  const float* gb = gate + (size_t)b * kN * 64 + lane;
  int s0 = start[r], s1 = start[r + 1];
  int len = s1 - s0;
  int per = (len + 3) >> 2;
  int e0 = s0 + w * per, e1 = min(e0 + per, s1);
  float acc = 0.f;
  int2 se;
  if (e0 < e1) se = edges[e0];
  for (int e = e0; e < e1; ++e) {
    int2 cur = se;
    if (e + 1 < e1) se = edges[e + 1];
    acc = fmaf(xb[(size_t)cur.x * 64], gb[(size_t)cur.y * 64], acc);
  }
  __shared__ float red[4][64];
  red[w][lane] = acc;
  __syncthreads();
  if (w == 0) {
    float a = red[0][lane] + red[1][lane] + red[2][lane] + red[3][lane];
    int r0 = batch[b * kNEG * 3 + 2];
    if (r == r0) a += 1.0f;
    agg[((size_t)g * kB * kR + blk) * 64 + lane] = a;
  }
}

// ---------------- rel conv: one block per row, wave = group, 8-deep load pipeline ----------------
__global__ void __launch_bounds__(256) k_conv_rel2(
    float* __restrict__ rel_x, const float* __restrict__ agg,
    fp rlw, fp rlb, fp rlns, fp rlnb, int layer) {
  int row = blockIdx.x;               // b*256+r (1024 blocks)
  int g = threadIdx.x >> 6, lane = threadIdx.x & 63;
  int pg = g * kL + layer;
  float xr = rel_x[(size_t)row * 64 + lane];
  float ag = agg[((size_t)g * kB * kR + row) * 64 + lane];
  fp w1 = rlw + (size_t)pg * 8192;
  float o = rlb[pg * 64 + lane];
  float wbuf[8];
  #pragma unroll
  for (int kk = 0; kk < 128; kk += 8) {
    #pragma unroll
    for (int u = 0; u < 8; ++u) wbuf[u] = w1[(kk + u) * 64 + lane];
    #pragma unroll
    for (int u = 0; u < 8; ++u) {
      int k = kk + u;
      float xv = (k < 64) ? rdlane(xr, k) : rdlane(ag, k - 64);
      o = fmaf(xv, wbuf[u], o);
    }
  }
  float m = wave_sum64(o) * (1.f / 64.f);
  float c = o - m;
  float v = wave_sum64(c * c) * (1.f / 64.f);
  float y = fmaxf(c * rsqrtf(v + 1e-5f) * rlns[pg * 64 + lane] + rlnb[pg * 64 + lane], 0.f);
  __shared__ float red[4][64];
  red[g][lane] = y;
  __syncthreads();
  if (g == 0)
    rel_x[(size_t)row * 64 + lane] = xr + red[0][lane] + red[1][lane] + red[2][lane] + red[3][lane];
}

// ---------------- fused entity layer ----------------
template<bool FIRST>
__global__ void __launch_bounds__(256) k_ent_layer2(
    const float* __restrict__ xcur, float* __restrict__ xnext,
    const float* __restrict__ gateL,
    const int* __restrict__ start, const int2* __restrict__ edges,
    const float* __restrict__ q, const int* __restrict__ batch,
    fp lw, fp lb, fp lns, fp lnb) {
  int n = (blockIdx.x * blockDim.x + threadIdx.x) >> 6;
  if (n >= kN) return;
  int lane = threadIdx.x & 63;
  int h0[4]; float qv[4];
  #pragma unroll
  for (int b = 0; b < 4; ++b) { h0[b] = batch[b * kNEG * 3]; qv[b] = q[b * 64 + lane]; }
  float a0 = 0.f, a1 = 0.f, a2 = 0.f, a3 = 0.f;
  int s0 = start[n], s1 = start[n + 1];
  int2 se;
  if (s0 < s1) se = edges[s0];
  for (int e = s0; e < s1; ++e) {
    int2 cur = se;
    if (e + 1 < s1) se = edges[e + 1];
    const float* gp = gateL + (size_t)cur.y * 64 + lane;
    if (FIRST) {
      if (cur.x == h0[0]) a0 = fmaf(qv[0], gp[0],     a0);
      if (cur.x == h0[1]) a1 = fmaf(qv[1], gp[16384], a1);
      if (cur.x == h0[2]) a2 = fmaf(qv[2], gp[32768], a2);
      if (cur.x == h0[3]) a3 = fmaf(qv[3], gp[49152], a3);
    } else {
      const float* xp = xcur + (size_t)cur.x * 64 + lane;
      a0 = fmaf(xp[0],       gp[0],     a0);
      a1 = fmaf(xp[640000],  gp[16384], a1);
      a2 = fmaf(xp[1280000], gp[32768], a2);
      a3 = fmaf(xp[1920000], gp[49152], a3);
    }
  }
  if (n == h0[0]) a0 += qv[0];
  if (n == h0[1]) a1 += qv[1];
  if (n == h0[2]) a2 += qv[2];
  if (n == h0[3]) a3 += qv[3];
  float x0, x1, x2, x3;
  if (FIRST) {
    x0 = (n == h0[0]) ? qv[0] : 0.f; x1 = (n == h0[1]) ? qv[1] : 0.f;
    x2 = (n == h0[2]) ? qv[2] : 0.f; x3 = (n == h0[3]) ? qv[3] : 0.f;
  } else {
    const float* xp = xcur + (size_t)n * 64 + lane;
    x0 = xp[0]; x1 = xp[640000]; x2 = xp[1280000]; x3 = xp[1920000];
  }
  float bv = lb[lane];
  float o0 = bv, o1 = bv, o2 = bv, o3 = bv;
  float wbuf[8];
  #pragma unroll
  for (int kk = 0; kk < 128; kk += 8) {
    #pragma unroll
    for (int u = 0; u < 8; ++u) wbuf[u] = lw[(kk + u) * 64 + lane];
    #pragma unroll
    for (int u = 0; u < 8; ++u) {
      int k = kk + u; float w = wbuf[u];
      if (k < 64) {
        o0 = fmaf(rdlane(x0, k), w, o0); o1 = fmaf(rdlane(x1, k), w, o1);
        o2 = fmaf(rdlane(x2, k), w, o2); o3 = fmaf(rdlane(x3, k), w, o3);
      } else {
        o0 = fmaf(rdlane(a0, k - 64), w, o0); o1 = fmaf(rdlane(a1, k - 64), w, o1);
        o2 = fmaf(rdlane(a2, k - 64), w, o2); o3 = fmaf(rdlane(a3, k - 64), w, o3);
      }
    }
  }
  float s = lns[lane], t = lnb[lane];
  float* yp = xnext + (size_t)n * 64 + lane;
  { float m = wave_sum64(o0) * (1.f/64.f); float c = o0 - m;
    float v = wave_sum64(c*c) * (1.f/64.f);
    yp[0] = x0 + fmaxf(c * rsqrtf(v + 1e-5f) * s + t, 0.f); }
  { float m = wave_sum64(o1) * (1.f/64.f); float c = o1 - m;
    float v = wave_sum64(c*c) * (1.f/64.f);
    yp[640000] = x1 + fmaxf(c * rsqrtf(v + 1e-5f) * s + t, 0.f); }
  { float m = wave_sum64(o2) * (1.f/64.f); float c = o2 - m;
    float v = wave_sum64(c*c) * (1.f/64.f);
    yp[1280000] = x2 + fmaxf(c * rsqrtf(v + 1e-5f) * s + t, 0.f); }
  { float m = wave_sum64(o3) * (1.f/64.f); float c = o3 - m;
    float v = wave_sum64(c*c) * (1.f/64.f);
    yp[1920000] = x3 + fmaxf(c * rsqrtf(v + 1e-5f) * s + t, 0.f); }
}

// ---------------- node_reps = concat(ent_x, q)@nmw + nmb ----------------
__global__ void __launch_bounds__(256) k_nodeup4(
    const float* __restrict__ x, const float* __restrict__ q,
    fp nmw, fp nmb, float* __restrict__ out) {
  int wid = (blockIdx.x * blockDim.x + threadIdx.x) >> 6;
  int lane = threadIdx.x & 63;
  int r0 = wid * 4;
  if (r0 >= kB * kN) return;
  int b = r0 / kN;
  const float* ip = x + (size_t)r0 * 64 + lane;
  float x0 = ip[0], x1 = ip[64], x2 = ip[128], x3 = ip[192];
  float qv = q[b * 64 + lane];
  float bv = nmb[lane];
  float c0 = bv, c1 = bv, c2 = bv, c3 = bv;
  float wbuf[4];
  #pragma unroll
  for (int kk = 0; kk < 64; kk += 4) {
    #pragma unroll
    for (int u = 0; u < 4; ++u) wbuf[u] = nmw[(kk + u) * 64 + lane];
    #pragma unroll
    for (int u = 0; u < 4; ++u) {
      int k = kk + u; float w = wbuf[u];
      c0 = fmaf(rdlane(x0, k), w, c0); c1 = fmaf(rdlane(x1, k), w, c1);
      c2 = fmaf(rdlane(x2, k), w, c2); c3 = fmaf(rdlane(x3, k), w, c3);
    }
  }
  float qa = 0.f;
  #pragma unroll
  for (int k = 0; k < 64; ++k)
    qa = fmaf(rdlane(qv, k), nmw[(64 + k) * 64 + lane], qa);
  float* op = out + (size_t)r0 * 64 + lane;
  op[0] = c0 + qa; op[64] = c1 + qa; op[128] = c2 + qa; op[192] = c3 + qa;
}

// ---------------- final scoring ----------------
__global__ void k_score(const float* __restrict__ entx, const float* __restrict__ q,
                        const int* __restrict__ batch,
                        fp m1w, fp m1b, fp m2w, fp m2b,
                        float* __restrict__ out) {
  int b = blockIdx.x / kNEG, n = blockIdx.x % kNEG;
  int t = batch[(b * kNEG + n) * 3 + 1];
  int j = threadIdx.x;  // 0..127
  __shared__ float gv[128];
  __shared__ float red[2];
  gv[j] = (j < 64) ? entx[((size_t)b * kN + t) * 64 + j] : q[b * 64 + (j - 64)];
  __syncthreads();
  float acc = m1b[j];
  #pragma unroll 16
  for (int k = 0; k < 128; ++k)
    acc = fmaf(gv[k], m1w[k * 128 + j], acc);
  float h = fmaxf(acc, 0.f) * m2w[j];
  h = wave_sum64(h);
  if ((j & 63) == 0) red[j >> 6] = h;
  __syncthreads();
  if (j == 0) out[b * kNEG + n] = red[0] + red[1] + m2b[0];
}

// ---------------- host ----------------
extern "C" void kernel_launch(void* const* d_in, const int* in_sizes, int n_in,
                              void* d_out, int out_size, void* d_ws, size_t ws_size,
                              hipStream_t stream) {
  const int* edge_src  = (const int*)d_in[0];
  const int* edge_dst  = (const int*)d_in[1];
  const int* edge_type = (const int*)d_in[2];
  const int* rel_src   = (const int*)d_in[3];
  const int* rel_dst   = (const int*)d_in[4];
  const int* rel_etype = (const int*)d_in[5];
  const int* batch     = (const int*)d_in[6];
  fp e1p1w = (fp)d_in[7],  e1p1b = (fp)d_in[8],  e1p2w = (fp)d_in[9],  e1p2b = (fp)d_in[10];
  fp e1lw  = (fp)d_in[11], e1lb  = (fp)d_in[12], e1lns = (fp)d_in[13], e1lnb = (fp)d_in[14];
  fp e2p1w = (fp)d_in[15], e2p1b = (fp)d_in[16], e2p2w = (fp)d_in[17], e2p2b = (fp)d_in[18];
  fp e2lw  = (fp)d_in[19], e2lb  = (fp)d_in[20], e2lns = (fp)d_in[21], e2lnb = (fp)d_in[22];
  fp e2m1w = (fp)d_in[23], e2m1b = (fp)d_in[24], e2m2w = (fp)d_in[25], e2m2b = (fp)d_in[26];
  fp rp1w  = (fp)d_in[27], rp1b  = (fp)d_in[28], rp2w  = (fp)d_in[29], rp2b  = (fp)d_in[30];
  fp rlw   = (fp)d_in[31], rlb   = (fp)d_in[32], rlns  = (fp)d_in[33], rlnb  = (fp)d_in[34];
  fp nmw   = (fp)d_in[35], nmb   = (fp)d_in[36];

  float* ws = (float*)d_ws;
  float* rel_x     = ws;                           // 65,536
  float* q         = rel_x + 65536;                // 256
  float* gate0     = q + 256;                      // 256
  float* gateR6    = gate0 + 256;                  // 6*65,536 = 393,216
  float* rel_agg   = gateR6 + 393216;              // 4*65,536 = 262,144
  float* node_reps = rel_agg + 262144;             // 2,560,000
  float* gateN     = node_reps + 2560000;          // 4*2,560,000 = 10,240,000
  float* ent_xa    = gateN + 10240000;             // 2,560,000
  float* ent_xb    = ent_xa + 2560000;             // 2,560,000
  int*   iws       = (int*)(ent_xb + 2560000);
  int2*  ent_edges = (int2*)iws;                   // 400,000 ints
  int2*  rel_edges = (int2*)(iws + 400000);        // 640,000 ints
  int*   ent_cnt   = iws + 400000 + 640000;        // 10,000
  int*   ent_start = ent_cnt + 10000;              // 10,001
  int*   ent_cur   = ent_start + 10001;            // 10,001
  int*   rel_cnt   = ent_cur + 10001;              // 1,024
  int*   rel_start = rel_cnt + 1024;               // 4*257 = 1,028
  int*   rel_cur   = rel_start + 1028;             // 1,028
  float* rp1wT     = (float*)(rel_cur + 1028);     // 24*4096 = 98,304
  float* rp2wT     = rp1wT + 98304;                // 98,304

  const int nZero = 10000 + 10001 + 10001 + 1024;  // ent_cnt..rel_cnt inclusive
  // ---- CSR build + weight transposes ----
  k_zero_i<<<(nZero + 255) / 256, 256, 0, stream>>>(ent_cnt, nZero);
  k_hist<<<(kE + 255) / 256, 256, 0, stream>>>(edge_dst, kE, ent_cnt);
  k_hist_rel<<<dim3((kER + 255) / 256, 4), 256, 0, stream>>>(rel_dst, rel_cnt);
  k_scan_multi<<<1, 256, 0, stream>>>(ent_cnt, ent_start, ent_cur, 10000, 0, 0);
  k_scan_multi<<<4, 256, 0, stream>>>(rel_cnt, rel_start, rel_cur, 256, 256, 257);
  k_fill_csr<<<(kE + 255) / 256, 256, 0, stream>>>(edge_src, edge_dst, edge_type, kE, ent_cur, ent_edges);
  k_fill_csr_rel<<<dim3((kER + 255) / 256, 4), 256, 0, stream>>>(rel_src, rel_dst, rel_etype, rel_cur, rel_edges);
  k_transpose64<<<24, 256, 0, stream>>>(rp1w, rp1wT);
  k_transpose64<<<24, 256, 0, stream>>>(rp2w, rp2wT);

  // ---- rel_x = one-hot boundary ----
  k_fill<<<256, 256, 0, stream>>>(rel_x, 0.f, kB * kR * kD);
  k_add_row<<<1, 256, 0, stream>>>(rel_x, batch);

  // ---- i = 0 (node_reps == ones) ----
  k_gate0<<<1, 256, 0, stream>>>(rp1w, rp1b, rp2w, rp2b, gate0);
  k_rel_agg0<<<1024, 256, 0, stream>>>(rel_start, rel_edges, batch, gate0, rel_agg);
  k_conv_rel2<<<1024, 256, 0, stream>>>(rel_x, rel_agg, rlw, rlb, rlns, rlnb, 0);

  // ---- entity_bf with e1 params -> node_reps ----
  k_get_q<<<1, 256, 0, stream>>>(q, rel_x, batch);
  k_mlp_rel6<<<dim3(256, 6), 256, 0, stream>>>(rel_x, e1p1w, e1p1b, e1p2w, e1p2b, gateR6);
  {
    float* cur = ent_xa; float* nxt = ent_xb;
    for (int j = 0; j < kL; ++j) {
      const float* gL = gateR6 + (size_t)j * kB * kR * 64;
      if (j == 0)
        k_ent_layer2<true><<<2500, 256, 0, stream>>>(cur, nxt, gL, ent_start, ent_edges, q, batch,
            e1lw + (size_t)j * 8192, e1lb + (size_t)j * 64, e1lns + (size_t)j * 64, e1lnb + (size_t)j * 64);
      else
        k_ent_layer2<false><<<2500, 256, 0, stream>>>(cur, nxt, gL, ent_start, ent_edges, q, batch,
            e1lw + (size_t)j * 8192, e1lb + (size_t)j * 64, e1lns + (size_t)j * 64, e1lnb + (size_t)j * 64);
      float* tmp = cur; cur = nxt; nxt = tmp;
    }
    k_nodeup4<<<2500, 256, 0, stream>>>(cur, q, nmw, nmb, node_reps);
  }

  // ---- i = 1..5 ----
  for (int i = 1; i < kL; ++i) {
    k_mlp_rowsT<<<dim3(625, 4), 64, 0, stream>>>(node_reps, rp1wT, rp1b, rp2wT, rp2b, i, gateN);
    k_gather_rel_all<<<dim3(1024, 4), 256, 0, stream>>>(rel_x, gateN, rel_start, rel_edges, batch, rel_agg);
    k_conv_rel2<<<1024, 256, 0, stream>>>(rel_x, rel_agg, rlw, rlb, rlns, rlnb, i);
  }

  // ---- entity_bf with e2 params + scoring ----
  k_get_q<<<1, 256, 0, stream>>>(q, rel_x, batch);
  k_mlp_rel6<<<dim3(256, 6), 256, 0, stream>>>(rel_x, e2p1w, e2p1b, e2p2w, e2p2b, gateR6);
  {
    float* cur = ent_xa; float* nxt = ent_xb;
    for (int j = 0; j < kL; ++j) {
      const float* gL = gateR6 + (size_t)j * kB * kR * 64;
      if (j == 0)
        k_ent_layer2<true><<<2500, 256, 0, stream>>>(cur, nxt, gL, ent_start, ent_edges, q, batch,
            e2lw + (size_t)j * 8192, e2lb + (size_t)j * 64, e2lns + (size_t)j * 64, e2lnb + (size_t)j * 64);
      else
        k_ent_layer2<false><<<2500, 256, 0, stream>>>(cur, nxt, gL, ent_start, ent_edges, q, batch,
            e2lw + (size_t)j * 8192, e2lb + (size_t)j * 64, e2lns + (size_t)j * 64, e2lnb + (size_t)j * 64);
      float* tmp = cur; cur = nxt; nxt = tmp;
    }
    k_score<<<kB * kNEG, 128, 0, stream>>>(cur, q, batch, e2m1w, e2m1b, e2m2w, e2m2b, (float*)d_out);
  }
}

// Round 8
// 1277.349 us; speedup vs baseline: 1.6757x; 1.6757x over previous
//
#include <hip/hip_runtime.h>

constexpr int kB   = 4;
constexpr int kNEG = 33;
constexpr int kN   = 10000;
constexpr int kR   = 256;
constexpr int kD   = 64;
constexpr int kL   = 6;
constexpr int kE   = 200000;
constexpr int kER  = 80000;

typedef const float* fp;
typedef __attribute__((ext_vector_type(8))) short bf16x8;
typedef __attribute__((ext_vector_type(4))) float f32x4;

__device__ __forceinline__ float rdlane(float v, int l) {
  return __uint_as_float(__builtin_amdgcn_readlane(__float_as_uint(v), l));
}
__device__ __forceinline__ float wave_sum64(float v) {
  #pragma unroll
  for (int o = 32; o > 0; o >>= 1) v += __shfl_xor(v, o, 64);
  return v;
}
// manual bf16 (RNE) — bf16 = top 16 bits of f32
__device__ __forceinline__ short f2bf(float x) {
  unsigned u = __float_as_uint(x);
  unsigned r = (u + 0x7fffu + ((u >> 16) & 1u)) >> 16;
  return (short)r;
}
__device__ __forceinline__ float bf2f(short s) {
  return __uint_as_float(((unsigned)(unsigned short)s) << 16);
}

// ---------------- utility ----------------
__global__ void k_fill(float* __restrict__ p, float v, int n) {
  int i = blockIdx.x * blockDim.x + threadIdx.x;
  int stride = gridDim.x * blockDim.x;
  for (; i < n; i += stride) p[i] = v;
}
__global__ void k_zero_i(int* __restrict__ p, int n) {
  int i = blockIdx.x * blockDim.x + threadIdx.x;
  int stride = gridDim.x * blockDim.x;
  for (; i < n; i += stride) p[i] = 0;
}
__global__ void k_add_row(float* __restrict__ dst, const int* __restrict__ batch) {
  int tid = threadIdx.x;
  int b = tid >> 6, d = tid & 63;
  int row = batch[b * kNEG * 3 + 2];
  dst[((size_t)b * kR + row) * 64 + d] += 1.0f;
}
__global__ void k_get_q(float* __restrict__ q, const float* __restrict__ relx,
                        const int* __restrict__ batch) {
  int tid = threadIdx.x;
  int b = tid >> 6, d = tid & 63;
  int r0 = batch[b * kNEG * 3 + 2];
  q[b * 64 + d] = relx[((size_t)b * kR + r0) * 64 + d];
}

// ---------------- CSR build ----------------
__global__ void k_hist(const int* __restrict__ dst, int ne, int* __restrict__ cnt) {
  int i = blockIdx.x * blockDim.x + threadIdx.x;
  if (i < ne) atomicAdd(&cnt[dst[i]], 1);
}
__global__ void k_hist_rel(const int* __restrict__ rel_dst, int* __restrict__ cnt) {
  int g = blockIdx.y;
  int i = blockIdx.x * blockDim.x + threadIdx.x;
  if (i < kER) atomicAdd(&cnt[g * 256 + rel_dst[(size_t)g * kER + i]], 1);
}
__global__ void k_scan_multi(const int* __restrict__ cnt, int* __restrict__ start,
                             int* __restrict__ cursor, int n, int cstride, int sstride) {
  const int* c = cnt + (size_t)blockIdx.x * cstride;
  int* st = start + (size_t)blockIdx.x * sstride;
  int* cu = cursor + (size_t)blockIdx.x * sstride;
  __shared__ int part[256];
  int t = threadIdx.x;
  int chunk = (n + 255) / 256;
  int lo = t * chunk, hi = min(lo + chunk, n);
  int s = 0;
  for (int i = lo; i < hi; ++i) s += c[i];
  part[t] = s;
  __syncthreads();
  if (t == 0) { int run = 0; for (int i = 0; i < 256; ++i) { int v = part[i]; part[i] = run; run += v; } }
  __syncthreads();
  int run = part[t];
  for (int i = lo; i < hi; ++i) { st[i] = run; cu[i] = run; run += c[i]; }
  if (t == 255) st[n] = run;
}
__global__ void k_fill_csr(const int* __restrict__ src, const int* __restrict__ dst,
                           const int* __restrict__ et, int ne,
                           int* __restrict__ cursor, int2* __restrict__ out) {
  int i = blockIdx.x * blockDim.x + threadIdx.x;
  if (i < ne) {
    int p = atomicAdd(&cursor[dst[i]], 1);
    out[p] = make_int2(src[i], et[i]);
  }
}
__global__ void k_fill_csr_rel(const int* __restrict__ src, const int* __restrict__ dst,
                               const int* __restrict__ et,
                               int* __restrict__ cursor, int2* __restrict__ out) {
  int g = blockIdx.y;
  int i = blockIdx.x * blockDim.x + threadIdx.x;
  if (i < kER) {
    int p = atomicAdd(&cursor[g * 257 + dst[(size_t)g * kER + i]], 1);
    out[(size_t)g * kER + p] = make_int2(src[(size_t)g * kER + i], et[(size_t)g * kER + i]);
  }
}

// ---------------- pack rel-gate weights into MFMA B-fragment order (bf16 hi/lo) ----------------
// frag element i = ((ks*4+nt)*64+lane)*8+t holds W[ks*32+(lane>>4)*8+t][nt*16+(lane&15)]
__global__ void k_packw(const float* __restrict__ w1, const float* __restrict__ w2,
                        short* __restrict__ w1h, short* __restrict__ w1l,
                        short* __restrict__ w2h, short* __restrict__ w2l) {
  int pg = blockIdx.x;
  for (int i = threadIdx.x; i < 4096; i += 256) {
    int t = i & 7, lane = (i >> 3) & 63, nt = (i >> 9) & 3, ks = i >> 11;
    int mr = lane & 15, kg = lane >> 4;
    int src = pg * 4096 + (ks * 32 + kg * 8 + t) * 64 + nt * 16 + mr;
    int dst = pg * 4096 + i;
    float v1 = w1[src]; short h1 = f2bf(v1);
    w1h[dst] = h1; w1l[dst] = f2bf(v1 - bf2f(h1));
    float v2 = w2[src]; short h2 = f2bf(v2);
    w2h[dst] = h2; w2l[dst] = f2bf(v2 - bf2f(h2));
  }
}

// ---------------- MFMA gate MLP (split-bf16): out[g] = relu(in@W1+b1)@W2+b2 ----------------
// block = 4 waves, wave = 16 rows; 16x16x32 bf16 MFMA; hi/lo split for fp32 accuracy
__global__ void __launch_bounds__(256) k_mlp_mfma(
    const float* __restrict__ in, const short* __restrict__ w1h, const short* __restrict__ w1l,
    const float* __restrict__ b1, const short* __restrict__ w2h, const short* __restrict__ w2l,
    const float* __restrict__ b2, int layer, float* __restrict__ out) {
  int g = blockIdx.y;
  int pg = g * kL + layer;
  int w = threadIdx.x >> 6, lane = threadIdx.x & 63;
  int mrow = lane & 15, kgrp = lane >> 4;
  int r0 = blockIdx.x * 64 + w * 16;
  __shared__ float hbuf[4][16][68];
  // layer-1 A frags: A[m][k], m=lane&15, k=(lane>>4)*8+t (contiguous)
  const float* xp = in + (size_t)(r0 + mrow) * 64 + kgrp * 8;
  bf16x8 a1h[2], a1l[2];
  #pragma unroll
  for (int ks = 0; ks < 2; ++ks) {
    #pragma unroll
    for (int t = 0; t < 8; ++t) {
      float v = xp[ks * 32 + t];
      short h = f2bf(v); a1h[ks][t] = h; a1l[ks][t] = f2bf(v - bf2f(h));
    }
  }
  const bf16x8* B1h = (const bf16x8*)(w1h + (size_t)pg * 4096);
  const bf16x8* B1l = (const bf16x8*)(w1l + (size_t)pg * 4096);
  #pragma unroll
  for (int nt = 0; nt < 4; ++nt) {
    f32x4 c = {0.f, 0.f, 0.f, 0.f};
    #pragma unroll
    for (int ks = 0; ks < 2; ++ks) {
      bf16x8 bh = B1h[(ks * 4 + nt) * 64 + lane];
      bf16x8 bl = B1l[(ks * 4 + nt) * 64 + lane];
      c = __builtin_amdgcn_mfma_f32_16x16x32_bf16(a1h[ks], bh, c, 0, 0, 0);
      c = __builtin_amdgcn_mfma_f32_16x16x32_bf16(a1h[ks], bl, c, 0, 0, 0);
      c = __builtin_amdgcn_mfma_f32_16x16x32_bf16(a1l[ks], bh, c, 0, 0, 0);
    }
    int col = nt * 16 + mrow;            // C: col=lane&15, row=(lane>>4)*4+reg (verified layout)
    float bv = b1[pg * 64 + col];
    #pragma unroll
    for (int rg = 0; rg < 4; ++rg)
      hbuf[w][kgrp * 4 + rg][col] = fmaxf(c[rg] + bv, 0.f);
  }
  __syncthreads();
  // layer-2 A frags from LDS (row-major 16x68, 16B-aligned rows)
  bf16x8 a2h[2], a2l[2];
  #pragma unroll
  for (int ks = 0; ks < 2; ++ks) {
    #pragma unroll
    for (int t = 0; t < 8; ++t) {
      float v = hbuf[w][mrow][ks * 32 + kgrp * 8 + t];
      short h = f2bf(v); a2h[ks][t] = h; a2l[ks][t] = f2bf(v - bf2f(h));
    }
  }
  const bf16x8* B2h = (const bf16x8*)(w2h + (size_t)pg * 4096);
  const bf16x8* B2l = (const bf16x8*)(w2l + (size_t)pg * 4096);
  float* ob = out + (size_t)g * kB * kN * 64;
  #pragma unroll
  for (int nt = 0; nt < 4; ++nt) {
    f32x4 c = {0.f, 0.f, 0.f, 0.f};
    #pragma unroll
    for (int ks = 0; ks < 2; ++ks) {
      bf16x8 bh = B2h[(ks * 4 + nt) * 64 + lane];
      bf16x8 bl = B2l[(ks * 4 + nt) * 64 + lane];
      c = __builtin_amdgcn_mfma_f32_16x16x32_bf16(a2h[ks], bh, c, 0, 0, 0);
      c = __builtin_amdgcn_mfma_f32_16x16x32_bf16(a2h[ks], bl, c, 0, 0, 0);
      c = __builtin_amdgcn_mfma_f32_16x16x32_bf16(a2l[ks], bh, c, 0, 0, 0);
    }
    int col = nt * 16 + mrow;
    float bv = b2[pg * 64 + col];
    #pragma unroll
    for (int rg = 0; rg < 4; ++rg)
      ob[(size_t)(r0 + kgrp * 4 + rg) * 64 + col] = c[rg] + bv;
  }
}

// ---------------- rel-gate MLP for entity phase: all 6 layers, row per wave ----------------
__global__ void __launch_bounds__(256) k_mlp_rel6(
    const float* __restrict__ in, fp p1w, fp p1b, fp p2w, fp p2b,
    float* __restrict__ out) {
  int j = blockIdx.y;
  int row = blockIdx.x * 4 + (threadIdx.x >> 6);
  int lane = threadIdx.x & 63;
  fp W1 = p1w + (size_t)j * 4096;
  fp W2 = p2w + (size_t)j * 4096;
  float xv = in[(size_t)row * 64 + lane];
  float a = p1b[j * 64 + lane];
  float wbuf[8];
  #pragma unroll
  for (int kk = 0; kk < 64; kk += 8) {
    #pragma unroll
    for (int u = 0; u < 8; ++u) wbuf[u] = W1[(kk + u) * 64 + lane];
    #pragma unroll
    for (int u = 0; u < 8; ++u) a = fmaf(rdlane(xv, kk + u), wbuf[u], a);
  }
  a = fmaxf(a, 0.f);
  float c = p2b[j * 64 + lane];
  #pragma unroll
  for (int kk = 0; kk < 64; kk += 8) {
    #pragma unroll
    for (int u = 0; u < 8; ++u) wbuf[u] = W2[(kk + u) * 64 + lane];
    #pragma unroll
    for (int u = 0; u < 8; ++u) c = fmaf(rdlane(a, kk + u), wbuf[u], c);
  }
  out[((size_t)j * kB * kR + row) * 64 + lane] = c;
}

// ---------------- i=0 rel specials ----------------
__global__ void k_gate0(fp p1w, fp p1b, fp p2w, fp p2b, float* __restrict__ gate0) {
  int g = threadIdx.x >> 6, lane = threadIdx.x & 63;
  int pg = g * kL;
  float a = p1b[pg * 64 + lane];
  #pragma unroll
  for (int k = 0; k < 64; ++k) a += p1w[(size_t)pg * 4096 + k * 64 + lane];
  a = fmaxf(a, 0.f);
  float c = p2b[pg * 64 + lane];
  #pragma unroll
  for (int k = 0; k < 64; ++k)
    c = fmaf(rdlane(a, k), p2w[(size_t)pg * 4096 + k * 64 + lane], c);
  gate0[g * 64 + lane] = c;
}
__global__ void k_rel_agg0(const int* __restrict__ rel_start, const int2* __restrict__ rel_edges,
                           const int* __restrict__ batch, const float* __restrict__ gate0,
                           float* __restrict__ agg) {
  int wid = (blockIdx.x * blockDim.x + threadIdx.x) >> 6;
  int lane = threadIdx.x & 63;
  int g = wid >> 10, rem = wid & 1023, b = rem >> 8, r = rem & 255;
  int r0 = batch[b * kNEG * 3 + 2];
  const int* start = rel_start + g * 257;
  const int2* edges = rel_edges + (size_t)g * kER;
  int s0 = start[r], s1 = start[r + 1];
  int cnt = 0;
  for (int base = s0; base < s1; base += 64) {
    int e = base + lane;
    bool m = false;
    if (e < s1) m = (edges[e].x == r0);
    cnt += (int)__popcll(__ballot(m));
  }
  agg[(size_t)wid * 64 + lane] = gate0[g * 64 + lane] * (float)cnt + ((r == r0) ? 1.f : 0.f);
}

// ---------------- rel gather (dense gates), blockIdx.y = g ----------------
__global__ void __launch_bounds__(256) k_gather_rel_all(
    const float* __restrict__ x, const float* __restrict__ gateN,
    const int* __restrict__ rel_start, const int2* __restrict__ rel_edges,
    const int* __restrict__ batch, float* __restrict__ agg) {
  int g = blockIdx.y;
  const float* gate = gateN + (size_t)g * kB * kN * 64;
  const int* start = rel_start + g * 257;
  const int2* edges = rel_edges + (size_t)g * kER;
  int blk = blockIdx.x;
  int b = blk >> 8, r = blk & 255;
  int w = threadIdx.x >> 6, lane = threadIdx.x & 63;
  const float* xb = x + (size_t)b * kR * 64 + lane;
  const float* gb = gate + (size_t)b * kN * 64 + lane;
  int s0 = start[r], s1 = start[r + 1];
  int len = s1 - s0;
  int per = (len + 3) >> 2;
  int e0 = s0 + w * per, e1 = min(e0 + per, s1);
  float acc = 0.f;
  int2 se;
  if (e0 < e1) se = edges[e0];
  for (int e = e0; e < e1; ++e) {
    int2 cur = se;
    if (e + 1 < e1) se = edges[e + 1];
    acc = fmaf(xb[(size_t)cur.x * 64], gb[(size_t)cur.y * 64], acc);
  }
  __shared__ float red[4][64];
  red[w][lane] = acc;
  __syncthreads();
  if (w == 0) {
    float a = red[0][lane] + red[1][lane] + red[2][lane] + red[3][lane];
    int r0 = batch[b * kNEG * 3 + 2];
    if (r == r0) a += 1.0f;
    agg[((size_t)g * kB * kR + blk) * 64 + lane] = a;
  }
}

// ---------------- rel conv: one block per row, wave = group, 8-deep load pipeline ----------------
__global__ void __launch_bounds__(256) k_conv_rel2(
    float* __restrict__ rel_x, const float* __restrict__ agg,
    fp rlw, fp rlb, fp rlns, fp rlnb, int layer) {
  int row = blockIdx.x;
  int g = threadIdx.x >> 6, lane = threadIdx.x & 63;
  int pg = g * kL + layer;
  float xr = rel_x[(size_t)row * 64 + lane];
  float ag = agg[((size_t)g * kB * kR + row) * 64 + lane];
  fp w1 = rlw + (size_t)pg * 8192;
  float o = rlb[pg * 64 + lane];
  float wbuf[8];
  #pragma unroll
  for (int kk = 0; kk < 128; kk += 8) {
    #pragma unroll
    for (int u = 0; u < 8; ++u) wbuf[u] = w1[(kk + u) * 64 + lane];
    #pragma unroll
    for (int u = 0; u < 8; ++u) {
      int k = kk + u;
      float xv = (k < 64) ? rdlane(xr, k) : rdlane(ag, k - 64);
      o = fmaf(xv, wbuf[u], o);
    }
  }
  float m = wave_sum64(o) * (1.f / 64.f);
  float c = o - m;
  float v = wave_sum64(c * c) * (1.f / 64.f);
  float y = fmaxf(c * rsqrtf(v + 1e-5f) * rlns[pg * 64 + lane] + rlnb[pg * 64 + lane], 0.f);
  __shared__ float red[4][64];
  red[g][lane] = y;
  __syncthreads();
  if (g == 0)
    rel_x[(size_t)row * 64 + lane] = xr + red[0][lane] + red[1][lane] + red[2][lane] + red[3][lane];
}

// ---------------- fused entity layer ----------------
template<bool FIRST>
__global__ void __launch_bounds__(256) k_ent_layer2(
    const float* __restrict__ xcur, float* __restrict__ xnext,
    const float* __restrict__ gateL,
    const int* __restrict__ start, const int2* __restrict__ edges,
    const float* __restrict__ q, const int* __restrict__ batch,
    fp lw, fp lb, fp lns, fp lnb) {
  int n = (blockIdx.x * blockDim.x + threadIdx.x) >> 6;
  if (n >= kN) return;
  int lane = threadIdx.x & 63;
  int h0[4]; float qv[4];
  #pragma unroll
  for (int b = 0; b < 4; ++b) { h0[b] = batch[b * kNEG * 3]; qv[b] = q[b * 64 + lane]; }
  float a0 = 0.f, a1 = 0.f, a2 = 0.f, a3 = 0.f;
  int s0 = start[n], s1 = start[n + 1];
  int2 se;
  if (s0 < s1) se = edges[s0];
  for (int e = s0; e < s1; ++e) {
    int2 cur = se;
    if (e + 1 < s1) se = edges[e + 1];
    const float* gp = gateL + (size_t)cur.y * 64 + lane;
    if (FIRST) {
      if (cur.x == h0[0]) a0 = fmaf(qv[0], gp[0],     a0);
      if (cur.x == h0[1]) a1 = fmaf(qv[1], gp[16384], a1);
      if (cur.x == h0[2]) a2 = fmaf(qv[2], gp[32768], a2);
      if (cur.x == h0[3]) a3 = fmaf(qv[3], gp[49152], a3);
    } else {
      const float* xp = xcur + (size_t)cur.x * 64 + lane;
      a0 = fmaf(xp[0],       gp[0],     a0);
      a1 = fmaf(xp[640000],  gp[16384], a1);
      a2 = fmaf(xp[1280000], gp[32768], a2);
      a3 = fmaf(xp[1920000], gp[49152], a3);
    }
  }
  if (n == h0[0]) a0 += qv[0];
  if (n == h0[1]) a1 += qv[1];
  if (n == h0[2]) a2 += qv[2];
  if (n == h0[3]) a3 += qv[3];
  float x0, x1, x2, x3;
  if (FIRST) {
    x0 = (n == h0[0]) ? qv[0] : 0.f; x1 = (n == h0[1]) ? qv[1] : 0.f;
    x2 = (n == h0[2]) ? qv[2] : 0.f; x3 = (n == h0[3]) ? qv[3] : 0.f;
  } else {
    const float* xp = xcur + (size_t)n * 64 + lane;
    x0 = xp[0]; x1 = xp[640000]; x2 = xp[1280000]; x3 = xp[1920000];
  }
  float bv = lb[lane];
  float o0 = bv, o1 = bv, o2 = bv, o3 = bv;
  float wbuf[8];
  #pragma unroll
  for (int kk = 0; kk < 128; kk += 8) {
    #pragma unroll
    for (int u = 0; u < 8; ++u) wbuf[u] = lw[(kk + u) * 64 + lane];
    #pragma unroll
    for (int u = 0; u < 8; ++u) {
      int k = kk + u; float w = wbuf[u];
      if (k < 64) {
        o0 = fmaf(rdlane(x0, k), w, o0); o1 = fmaf(rdlane(x1, k), w, o1);
        o2 = fmaf(rdlane(x2, k), w, o2); o3 = fmaf(rdlane(x3, k), w, o3);
      } else {
        o0 = fmaf(rdlane(a0, k - 64), w, o0); o1 = fmaf(rdlane(a1, k - 64), w, o1);
        o2 = fmaf(rdlane(a2, k - 64), w, o2); o3 = fmaf(rdlane(a3, k - 64), w, o3);
      }
    }
  }
  float s = lns[lane], t = lnb[lane];
  float* yp = xnext + (size_t)n * 64 + lane;
  { float m = wave_sum64(o0) * (1.f/64.f); float c = o0 - m;
    float v = wave_sum64(c*c) * (1.f/64.f);
    yp[0] = x0 + fmaxf(c * rsqrtf(v + 1e-5f) * s + t, 0.f); }
  { float m = wave_sum64(o1) * (1.f/64.f); float c = o1 - m;
    float v = wave_sum64(c*c) * (1.f/64.f);
    yp[640000] = x1 + fmaxf(c * rsqrtf(v + 1e-5f) * s + t, 0.f); }
  { float m = wave_sum64(o2) * (1.f/64.f); float c = o2 - m;
    float v = wave_sum64(c*c) * (1.f/64.f);
    yp[1280000] = x2 + fmaxf(c * rsqrtf(v + 1e-5f) * s + t, 0.f); }
  { float m = wave_sum64(o3) * (1.f/64.f); float c = o3 - m;
    float v = wave_sum64(c*c) * (1.f/64.f);
    yp[1920000] = x3 + fmaxf(c * rsqrtf(v + 1e-5f) * s + t, 0.f); }
}

// ---------------- node_reps = concat(ent_x, q)@nmw + nmb ----------------
__global__ void __launch_bounds__(256) k_nodeup4(
    const float* __restrict__ x, const float* __restrict__ q,
    fp nmw, fp nmb, float* __restrict__ out) {
  int wid = (blockIdx.x * blockDim.x + threadIdx.x) >> 6;
  int lane = threadIdx.x & 63;
  int r0 = wid * 4;
  if (r0 >= kB * kN) return;
  int b = r0 / kN;
  const float* ip = x + (size_t)r0 * 64 + lane;
  float x0 = ip[0], x1 = ip[64], x2 = ip[128], x3 = ip[192];
  float qv = q[b * 64 + lane];
  float bv = nmb[lane];
  float c0 = bv, c1 = bv, c2 = bv, c3 = bv;
  float wbuf[4];
  #pragma unroll
  for (int kk = 0; kk < 64; kk += 4) {
    #pragma unroll
    for (int u = 0; u < 4; ++u) wbuf[u] = nmw[(kk + u) * 64 + lane];
    #pragma unroll
    for (int u = 0; u < 4; ++u) {
      int k = kk + u; float w = wbuf[u];
      c0 = fmaf(rdlane(x0, k), w, c0); c1 = fmaf(rdlane(x1, k), w, c1);
      c2 = fmaf(rdlane(x2, k), w, c2); c3 = fmaf(rdlane(x3, k), w, c3);
    }
  }
  float qa = 0.f;
  #pragma unroll
  for (int k = 0; k < 64; ++k)
    qa = fmaf(rdlane(qv, k), nmw[(64 + k) * 64 + lane], qa);
  float* op = out + (size_t)r0 * 64 + lane;
  op[0] = c0 + qa; op[64] = c1 + qa; op[128] = c2 + qa; op[192] = c3 + qa;
}

// ---------------- final scoring ----------------
__global__ void k_score(const float* __restrict__ entx, const float* __restrict__ q,
                        const int* __restrict__ batch,
                        fp m1w, fp m1b, fp m2w, fp m2b,
                        float* __restrict__ out) {
  int b = blockIdx.x / kNEG, n = blockIdx.x % kNEG;
  int t = batch[(b * kNEG + n) * 3 + 1];
  int j = threadIdx.x;
  __shared__ float gv[128];
  __shared__ float red[2];
  gv[j] = (j < 64) ? entx[((size_t)b * kN + t) * 64 + j] : q[b * 64 + (j - 64)];
  __syncthreads();
  float acc = m1b[j];
  #pragma unroll 16
  for (int k = 0; k < 128; ++k)
    acc = fmaf(gv[k], m1w[k * 128 + j], acc);
  float h = fmaxf(acc, 0.f) * m2w[j];
  h = wave_sum64(h);
  if ((j & 63) == 0) red[j >> 6] = h;
  __syncthreads();
  if (j == 0) out[b * kNEG + n] = red[0] + red[1] + m2b[0];
}

// ---------------- host ----------------
extern "C" void kernel_launch(void* const* d_in, const int* in_sizes, int n_in,
                              void* d_out, int out_size, void* d_ws, size_t ws_size,
                              hipStream_t stream) {
  const int* edge_src  = (const int*)d_in[0];
  const int* edge_dst  = (const int*)d_in[1];
  const int* edge_type = (const int*)d_in[2];
  const int* rel_src   = (const int*)d_in[3];
  const int* rel_dst   = (const int*)d_in[4];
  const int* rel_etype = (const int*)d_in[5];
  const int* batch     = (const int*)d_in[6];
  fp e1p1w = (fp)d_in[7],  e1p1b = (fp)d_in[8],  e1p2w = (fp)d_in[9],  e1p2b = (fp)d_in[10];
  fp e1lw  = (fp)d_in[11], e1lb  = (fp)d_in[12], e1lns = (fp)d_in[13], e1lnb = (fp)d_in[14];
  fp e2p1w = (fp)d_in[15], e2p1b = (fp)d_in[16], e2p2w = (fp)d_in[17], e2p2b = (fp)d_in[18];
  fp e2lw  = (fp)d_in[19], e2lb  = (fp)d_in[20], e2lns = (fp)d_in[21], e2lnb = (fp)d_in[22];
  fp e2m1w = (fp)d_in[23], e2m1b = (fp)d_in[24], e2m2w = (fp)d_in[25], e2m2b = (fp)d_in[26];
  fp rp1w  = (fp)d_in[27], rp1b  = (fp)d_in[28], rp2w  = (fp)d_in[29], rp2b  = (fp)d_in[30];
  fp rlw   = (fp)d_in[31], rlb   = (fp)d_in[32], rlns  = (fp)d_in[33], rlnb  = (fp)d_in[34];
  fp nmw   = (fp)d_in[35], nmb   = (fp)d_in[36];

  float* ws = (float*)d_ws;
  float* rel_x     = ws;                           // 65,536
  float* q         = rel_x + 65536;                // 256
  float* gate0     = q + 256;                      // 256
  float* gateR6    = gate0 + 256;                  // 393,216
  float* rel_agg   = gateR6 + 393216;              // 262,144
  float* node_reps = rel_agg + 262144;             // 2,560,000
  float* gateN     = node_reps + 2560000;          // 10,240,000
  float* ent_xa    = gateN + 10240000;             // 2,560,000
  float* ent_xb    = ent_xa + 2560000;             // 2,560,000
  int*   iws       = (int*)(ent_xb + 2560000);
  int2*  ent_edges = (int2*)iws;                   // 400,000 ints
  int2*  rel_edges = (int2*)(iws + 400000);        // 640,000 ints
  int*   ent_cnt   = iws + 400000 + 640000;        // 10,000
  int*   ent_start = ent_cnt + 10000;              // 10,001
  int*   ent_cur   = ent_start + 10001;            // 10,001
  int*   rel_cnt   = ent_cur + 10001;              // 1,024
  int*   rel_start = rel_cnt + 1024;               // 1,028
  int*   rel_cur   = rel_start + 1028;             // 1,028
  // +2 ints pad for 16B alignment of the packed-weight region
  short* w1hp      = (short*)(rel_cur + 1028 + 2); // 98,304 shorts each
  short* w1lp      = w1hp + 98304;
  short* w2hp      = w1lp + 98304;
  short* w2lp      = w2hp + 98304;

  const int nZero = 10000 + 10001 + 10001 + 1024;
  // ---- CSR build + weight packing ----
  k_zero_i<<<(nZero + 255) / 256, 256, 0, stream>>>(ent_cnt, nZero);
  k_hist<<<(kE + 255) / 256, 256, 0, stream>>>(edge_dst, kE, ent_cnt);
  k_hist_rel<<<dim3((kER + 255) / 256, 4), 256, 0, stream>>>(rel_dst, rel_cnt);
  k_scan_multi<<<1, 256, 0, stream>>>(ent_cnt, ent_start, ent_cur, 10000, 0, 0);
  k_scan_multi<<<4, 256, 0, stream>>>(rel_cnt, rel_start, rel_cur, 256, 256, 257);
  k_fill_csr<<<(kE + 255) / 256, 256, 0, stream>>>(edge_src, edge_dst, edge_type, kE, ent_cur, ent_edges);
  k_fill_csr_rel<<<dim3((kER + 255) / 256, 4), 256, 0, stream>>>(rel_src, rel_dst, rel_etype, rel_cur, rel_edges);
  k_packw<<<24, 256, 0, stream>>>(rp1w, rp2w, w1hp, w1lp, w2hp, w2lp);

  // ---- rel_x = one-hot boundary ----
  k_fill<<<256, 256, 0, stream>>>(rel_x, 0.f, kB * kR * kD);
  k_add_row<<<1, 256, 0, stream>>>(rel_x, batch);

  // ---- i = 0 (node_reps == ones) ----
  k_gate0<<<1, 256, 0, stream>>>(rp1w, rp1b, rp2w, rp2b, gate0);
  k_rel_agg0<<<1024, 256, 0, stream>>>(rel_start, rel_edges, batch, gate0, rel_agg);
  k_conv_rel2<<<1024, 256, 0, stream>>>(rel_x, rel_agg, rlw, rlb, rlns, rlnb, 0);

  // ---- entity_bf with e1 params -> node_reps ----
  k_get_q<<<1, 256, 0, stream>>>(q, rel_x, batch);
  k_mlp_rel6<<<dim3(256, 6), 256, 0, stream>>>(rel_x, e1p1w, e1p1b, e1p2w, e1p2b, gateR6);
  {
    float* cur = ent_xa; float* nxt = ent_xb;
    for (int j = 0; j < kL; ++j) {
      const float* gL = gateR6 + (size_t)j * kB * kR * 64;
      if (j == 0)
        k_ent_layer2<true><<<2500, 256, 0, stream>>>(cur, nxt, gL, ent_start, ent_edges, q, batch,
            e1lw + (size_t)j * 8192, e1lb + (size_t)j * 64, e1lns + (size_t)j * 64, e1lnb + (size_t)j * 64);
      else
        k_ent_layer2<false><<<2500, 256, 0, stream>>>(cur, nxt, gL, ent_start, ent_edges, q, batch,
            e1lw + (size_t)j * 8192, e1lb + (size_t)j * 64, e1lns + (size_t)j * 64, e1lnb + (size_t)j * 64);
      float* tmp = cur; cur = nxt; nxt = tmp;
    }
    k_nodeup4<<<2500, 256, 0, stream>>>(cur, q, nmw, nmb, node_reps);
  }

  // ---- i = 1..5 ----
  for (int i = 1; i < kL; ++i) {
    k_mlp_mfma<<<dim3(625, 4), 256, 0, stream>>>(node_reps, w1hp, w1lp, rp1b, w2hp, w2lp, rp2b, i, gateN);
    k_gather_rel_all<<<dim3(1024, 4), 256, 0, stream>>>(rel_x, gateN, rel_start, rel_edges, batch, rel_agg);
    k_conv_rel2<<<1024, 256, 0, stream>>>(rel_x, rel_agg, rlw, rlb, rlns, rlnb, i);
  }

  // ---- entity_bf with e2 params + scoring ----
  k_get_q<<<1, 256, 0, stream>>>(q, rel_x, batch);
  k_mlp_rel6<<<dim3(256, 6), 256, 0, stream>>>(rel_x, e2p1w, e2p1b, e2p2w, e2p2b, gateR6);
  {
    float* cur = ent_xa; float* nxt = ent_xb;
    for (int j = 0; j < kL; ++j) {
      const float* gL = gateR6 + (size_t)j * kB * kR * 64;
      if (j == 0)
        k_ent_layer2<true><<<2500, 256, 0, stream>>>(cur, nxt, gL, ent_start, ent_edges, q, batch,
            e2lw + (size_t)j * 8192, e2lb + (size_t)j * 64, e2lns + (size_t)j * 64, e2lnb + (size_t)j * 64);
      else
        k_ent_layer2<false><<<2500, 256, 0, stream>>>(cur, nxt, gL, ent_start, ent_edges, q, batch,
            e2lw + (size_t)j * 8192, e2lb + (size_t)j * 64, e2lns + (size_t)j * 64, e2lnb + (size_t)j * 64);
      float* tmp = cur; cur = nxt; nxt = tmp;
    }
    k_score<<<kB * kNEG, 128, 0, stream>>>(cur, q, batch, e2m1w, e2m1b, e2m2w, e2m2b, (float*)d_out);
  }
}